// Round 1
// baseline (5934.838 us; speedup 1.0000x reference)
//
#include <hip/hip_runtime.h>
#include <hip/hip_bf16.h>

#define NN  100000   // nodes
#define NE  800000   // edges
#define KIN 384      // input dim
#define HID 256      // hidden dim
#define BN_EPS 1e-5f

typedef __attribute__((ext_vector_type(4))) float floatx4;
typedef __attribute__((ext_vector_type(8))) short short8;

__device__ __forceinline__ unsigned short f2b(float f) {
    union { float f; unsigned int u; } v; v.f = f;
    unsigned int r = v.u + 0x7fffu + ((v.u >> 16) & 1u);   // round-to-nearest-even
    return (unsigned short)(r >> 16);
}
__device__ __forceinline__ float b2f(unsigned short h) {
    union { unsigned int u; float f; } v; v.u = ((unsigned int)h) << 16;
    return v.f;
}

// ---------------------------------------------------------------------------
// W [K][HID] fp32  ->  Wt [HID][K] bf16   (tiny; once per launch)
__global__ void k_wt(const float* __restrict__ W, unsigned short* __restrict__ Wt, int K) {
    int n = threadIdx.x;        // 0..255 output col
    int k = blockIdx.x;         // 0..K-1
    Wt[(size_t)n * K + k] = f2b(W[(size_t)k * HID + n]);
}

// in-degree count over dst
__global__ void k_count(const int* __restrict__ dst, int* __restrict__ deg) {
    int i = blockIdx.x * 256 + threadIdx.x;
    if (i < NE) atomicAdd(deg + dst[i], 1);
}

__global__ void k_dinv(const int* __restrict__ deg, float* __restrict__ dinv) {
    int i = blockIdx.x * 256 + threadIdx.x;
    if (i < NN) dinv[i] = rsqrtf((float)(deg[i] + 1));   // deg + self loop
}

// ---------------------------------------------------------------------------
// bf16 MFMA GEMM: C[M][HID](bf16) = A[M][K](fp32, optional BN+ReLU) * Bt^T
// Bt is [HID][K] bf16 (pre-transposed). MODE=1: A' = relu(A*scale[k]+bias[k]).
template<int K, int MODE>
__global__ __launch_bounds__(256) void k_gemm(
    const float* __restrict__ A, const unsigned short* __restrict__ Bt,
    unsigned short* __restrict__ C,
    const float* __restrict__ scale, const float* __restrict__ bias, int M)
{
    constexpr int BM = 128, BN = 128, BK = 32, LD = 40;  // LD=32+8 pad: kills LDS bank conflicts
    __shared__ __align__(16) unsigned short As[BM * LD];
    __shared__ __align__(16) unsigned short Bs[BN * LD];
    const int tid = threadIdx.x;
    const int lane = tid & 63;
    const int wid  = tid >> 6;
    const int wm = wid & 1, wn = wid >> 1;
    const int l15 = lane & 15, lq = lane >> 4;
    const int row0 = blockIdx.y * BM, col0 = blockIdx.x * BN;

    floatx4 acc[4][4] = {};

    const int ar = tid >> 3;        // 0..31 (row within 32-row stripe)
    const int ak = (tid & 7) * 4;   // 0..28 (k offset, floats)
    const int bn_ = tid >> 2;       // 0..63
    const int bk  = (tid & 3) * 8;  // 0,8,16,24 (bf16 elems)

    for (int k0 = 0; k0 < K; k0 += BK) {
        // ---- stage A: 128x32 fp32 -> bf16 (fused BN+ReLU for layer 2) ----
        float4 sv, bv;
        if (MODE) {
            sv = *(const float4*)(scale + k0 + ak);
            bv = *(const float4*)(bias  + k0 + ak);
        }
        #pragma unroll
        for (int p = 0; p < 4; ++p) {
            const int row  = p * 32 + ar;
            const int grow = row0 + row;
            float x0 = 0.f, x1 = 0.f, x2 = 0.f, x3 = 0.f;
            if (grow < M) {
                float4 v = *(const float4*)(A + (size_t)grow * K + k0 + ak);
                if (MODE) {
                    x0 = fmaxf(v.x * sv.x + bv.x, 0.f);
                    x1 = fmaxf(v.y * sv.y + bv.y, 0.f);
                    x2 = fmaxf(v.z * sv.z + bv.z, 0.f);
                    x3 = fmaxf(v.w * sv.w + bv.w, 0.f);
                } else { x0 = v.x; x1 = v.y; x2 = v.z; x3 = v.w; }
            }
            ushort4 o;
            o.x = f2b(x0); o.y = f2b(x1); o.z = f2b(x2); o.w = f2b(x3);
            *(ushort4*)(As + row * LD + ak) = o;
        }
        // ---- stage B: 128x32 bf16 copy-through (Bt already [n][k]) ----
        #pragma unroll
        for (int p = 0; p < 2; ++p) {
            const int n = p * 64 + bn_;
            *(float4*)(Bs + n * LD + bk) =
                *(const float4*)(Bt + (size_t)(col0 + n) * K + k0 + bk);
        }
        __syncthreads();

        // fragment loads: A[m=lane&15][k=(lane>>4)*8+j], B[n=lane&15][k=...]
        short8 af[4], bf[4];
        #pragma unroll
        for (int i = 0; i < 4; ++i)
            af[i] = *(const short8*)(As + (wm * 64 + i * 16 + l15) * LD + lq * 8);
        #pragma unroll
        for (int j = 0; j < 4; ++j)
            bf[j] = *(const short8*)(Bs + (wn * 64 + j * 16 + l15) * LD + lq * 8);
        #pragma unroll
        for (int i = 0; i < 4; ++i)
            #pragma unroll
            for (int j = 0; j < 4; ++j)
                acc[i][j] = __builtin_amdgcn_mfma_f32_16x16x32_bf16(af[i], bf[j], acc[i][j], 0, 0, 0);
        __syncthreads();
    }

    // epilogue: C/D layout col=lane&15, row=(lane>>4)*4+reg (m89-verified)
    #pragma unroll
    for (int i = 0; i < 4; ++i) {
        #pragma unroll
        for (int r = 0; r < 4; ++r) {
            const int m = row0 + wm * 64 + i * 16 + lq * 4 + r;
            if (m < M) {
                #pragma unroll
                for (int j = 0; j < 4; ++j) {
                    const int c = col0 + wn * 64 + j * 16 + l15;
                    C[(size_t)m * HID + c] = f2b(acc[i][j][r]);
                }
            }
        }
    }
}

// ---------------------------------------------------------------------------
// edge scatter: AGG[dst] += dinv[src]*dinv[dst] * H[src]   (one wave per edge)
__global__ __launch_bounds__(256) void k_scatter(
    const unsigned short* __restrict__ H, const int* __restrict__ src,
    const int* __restrict__ dst, const float* __restrict__ dinv,
    float* __restrict__ AGG)
{
    const int lane = threadIdx.x & 63;
    const int wid  = blockIdx.x * 4 + (threadIdx.x >> 6);
    const int nw   = gridDim.x * 4;
    for (int e = wid; e < NE; e += nw) {
        const int s = src[e], d = dst[e];
        const float coef = dinv[s] * dinv[d];
        const ushort4 hv = *(const ushort4*)(H + (size_t)s * HID + lane * 4);
        float* o = AGG + (size_t)d * HID + lane * 4;
        atomicAdd(o + 0, b2f(hv.x) * coef);
        atomicAdd(o + 1, b2f(hv.y) * coef);
        atomicAdd(o + 2, b2f(hv.z) * coef);
        atomicAdd(o + 3, b2f(hv.w) * coef);
    }
}

// ---------------------------------------------------------------------------
// self-loop add + BN stat accumulation: AGG += H/deg; per-col sum/sumsq
__global__ __launch_bounds__(256) void k_selfbn(
    float* __restrict__ AGG, const unsigned short* __restrict__ H,
    const float* __restrict__ dinv, float* __restrict__ bn_acc /* [2][256] */)
{
    constexpr int RPB = (NN + 511) / 512;   // 196
    const int c  = threadIdx.x;
    const int r0 = blockIdx.x * RPB;
    const int r1 = min(r0 + RPB, NN);
    float s = 0.f, q = 0.f;
    for (int r = r0; r < r1; ++r) {
        const float di = dinv[r];
        float v = AGG[(size_t)r * HID + c] + b2f(H[(size_t)r * HID + c]) * di * di;
        AGG[(size_t)r * HID + c] = v;
        s += v; q += v * v;
    }
    atomicAdd(bn_acc + c, s);
    atomicAdd(bn_acc + 256 + c, q);
}

__global__ void k_bnparam(const float* __restrict__ bn_acc,
                          const float* __restrict__ g, const float* __restrict__ be,
                          float* __restrict__ scale, float* __restrict__ bias)
{
    const int c = threadIdx.x;
    const float inv_n = 1.f / (float)NN;
    const float mu  = bn_acc[c] * inv_n;
    const float var = bn_acc[256 + c] * inv_n - mu * mu;
    const float sc  = g[c] * rsqrtf(var + BN_EPS);
    scale[c] = sc;
    bias[c]  = be[c] - sc * mu;
}

// final BN2 + ReLU -> d_out (fp32)
__global__ __launch_bounds__(256) void k_apply(
    const float* __restrict__ AGG, const float* __restrict__ scale,
    const float* __restrict__ bias, float* __restrict__ out)
{
    const int gid = blockIdx.x * 256 + threadIdx.x;   // one float4 / thread
    if (gid < NN * (HID / 4)) {
        const int c4 = (gid & 63) * 4;
        float4 v  = *(const float4*)(AGG + (size_t)gid * 4);
        float4 sc = *(const float4*)(scale + c4);
        float4 bi = *(const float4*)(bias + c4);
        float4 o;
        o.x = fmaxf(v.x * sc.x + bi.x, 0.f);
        o.y = fmaxf(v.y * sc.y + bi.y, 0.f);
        o.z = fmaxf(v.z * sc.z + bi.z, 0.f);
        o.w = fmaxf(v.w * sc.w + bi.w, 0.f);
        *(float4*)(out + (size_t)gid * 4) = o;
    }
}

// ---------------------------------------------------------------------------
extern "C" void kernel_launch(void* const* d_in, const int* in_sizes, int n_in,
                              void* d_out, int out_size, void* d_ws, size_t ws_size,
                              hipStream_t stream)
{
    const float* x   = (const float*)d_in[0];
    const int*   ei  = (const int*)d_in[1];
    const float* W1  = (const float*)d_in[2];
    // d_in[3] = b1: cancelled by BN mean subtraction
    const float* g1  = (const float*)d_in[4];
    const float* be1 = (const float*)d_in[5];
    const float* W2  = (const float*)d_in[6];
    // d_in[7] = b2: cancelled by BN
    const float* g2  = (const float*)d_in[8];
    const float* be2 = (const float*)d_in[9];
    float* out = (float*)d_out;
    const int* srcp = ei;
    const int* dstp = ei + NE;

    char* p = (char*)d_ws;
    float*          AGG  = (float*)p;           p += (size_t)NN * HID * 4;  // 102.4 MB
    unsigned short* H    = (unsigned short*)p;  p += (size_t)NN * HID * 2;  // 51.2 MB
    int*            deg  = (int*)p;             p += (size_t)NN * 4;
    float*          dinv = (float*)p;           p += (size_t)NN * 4;
    unsigned short* W1t  = (unsigned short*)p;  p += (size_t)KIN * HID * 2;
    unsigned short* W2t  = (unsigned short*)p;  p += (size_t)HID * HID * 2;
    float*          bn1  = (float*)p;           p += 512 * 4;
    float*          bn2  = (float*)p;           p += 512 * 4;
    float*          sc1  = (float*)p;           p += 256 * 4;
    float*          bi1  = (float*)p;           p += 256 * 4;
    float*          sc2  = (float*)p;           p += 256 * 4;
    float*          bi2  = (float*)p;           p += 256 * 4;

    hipMemsetAsync(AGG, 0, (size_t)NN * HID * 4, stream);
    hipMemsetAsync(deg, 0, (size_t)NN * 4, stream);
    hipMemsetAsync(bn1, 0, 1024 * 4, stream);   // bn1 + bn2 accumulators

    k_wt<<<KIN, HID, 0, stream>>>(W1, W1t, KIN);
    k_wt<<<HID, HID, 0, stream>>>(W2, W2t, HID);
    k_count<<<(NE + 255) / 256, 256, 0, stream>>>(dstp, deg);
    k_dinv<<<(NN + 255) / 256, 256, 0, stream>>>(deg, dinv);

    dim3 ggrid(HID / 128, (NN + 127) / 128);   // (2, 782)

    // ---- layer 1 ----
    k_gemm<KIN, 0><<<ggrid, 256, 0, stream>>>(x, W1t, H, nullptr, nullptr, NN);
    k_scatter<<<8192, 256, 0, stream>>>(H, srcp, dstp, dinv, AGG);
    k_selfbn<<<512, 256, 0, stream>>>(AGG, H, dinv, bn1);
    k_bnparam<<<1, 256, 0, stream>>>(bn1, g1, be1, sc1, bi1);

    // ---- layer 2 (BN1+ReLU fused into GEMM2 A-stage) ----
    k_gemm<HID, 1><<<ggrid, 256, 0, stream>>>(AGG, W2t, H, sc1, bi1, NN);
    hipMemsetAsync(AGG, 0, (size_t)NN * HID * 4, stream);
    k_scatter<<<8192, 256, 0, stream>>>(H, srcp, dstp, dinv, AGG);
    k_selfbn<<<512, 256, 0, stream>>>(AGG, H, dinv, bn2);
    k_bnparam<<<1, 256, 0, stream>>>(bn2, g2, be2, sc2, bi2);
    k_apply<<<(NN * HID / 4 + 255) / 256, 256, 0, stream>>>(AGG, sc2, bi2, out);
}

// Round 2
// 828.441 us; speedup vs baseline: 7.1639x; 7.1639x over previous
//
#include <hip/hip_runtime.h>
#include <hip/hip_bf16.h>

#define NN  100000   // nodes
#define NE  800000   // edges
#define KIN 384      // input dim
#define HID 256      // hidden dim
#define BN_EPS 1e-5f

typedef __attribute__((ext_vector_type(4))) float floatx4;
typedef __attribute__((ext_vector_type(8))) short short8;

__device__ __forceinline__ unsigned short f2b(float f) {
    union { float f; unsigned int u; } v; v.f = f;
    unsigned int r = v.u + 0x7fffu + ((v.u >> 16) & 1u);   // round-to-nearest-even
    return (unsigned short)(r >> 16);
}
__device__ __forceinline__ float b2f(unsigned short h) {
    union { unsigned int u; float f; } v; v.u = ((unsigned int)h) << 16;
    return v.f;
}

// ---------------------------------------------------------------------------
// W [K][HID] fp32  ->  Wt [HID][K] bf16
__global__ void k_wt(const float* __restrict__ W, unsigned short* __restrict__ Wt, int K) {
    int n = threadIdx.x;
    int k = blockIdx.x;
    Wt[(size_t)n * K + k] = f2b(W[(size_t)k * HID + n]);
}

// in-degree count over dst
__global__ void k_count(const int* __restrict__ dst, int* __restrict__ deg) {
    int i = blockIdx.x * 256 + threadIdx.x;
    if (i < NE) atomicAdd(deg + dst[i], 1);
}

__global__ void k_dinv(const int* __restrict__ deg, float* __restrict__ dinv) {
    int i = blockIdx.x * 256 + threadIdx.x;
    if (i < NN) dinv[i] = rsqrtf((float)(deg[i] + 1));   // deg + self loop
}

// ---------------------------------------------------------------------------
// hierarchical exclusive scan of deg[NN] -> rowptr[NN+1]
__device__ __forceinline__ int block_incl_scan(int v, int* lds) {  // 256 threads
    lds[threadIdx.x] = v; __syncthreads();
    #pragma unroll
    for (int off = 1; off < 256; off <<= 1) {
        int t = lds[threadIdx.x];
        int a = (threadIdx.x >= off) ? lds[threadIdx.x - off] : 0;
        __syncthreads();
        lds[threadIdx.x] = t + a;
        __syncthreads();
    }
    return lds[threadIdx.x];
}

__global__ __launch_bounds__(256) void k_scan1(const int* __restrict__ deg, int* __restrict__ bsum) {
    __shared__ int lds[256];
    int i = blockIdx.x * 256 + threadIdx.x;
    int v = (i < NN) ? deg[i] : 0;
    int incl = block_incl_scan(v, lds);
    if (threadIdx.x == 255) bsum[blockIdx.x] = incl;
}

__global__ __launch_bounds__(512) void k_scan2(const int* __restrict__ bsum,
                                               int* __restrict__ boff, int nb,
                                               int* __restrict__ rowptr) {
    __shared__ int lds[512];
    int v = (threadIdx.x < nb) ? bsum[threadIdx.x] : 0;
    lds[threadIdx.x] = v; __syncthreads();
    #pragma unroll
    for (int off = 1; off < 512; off <<= 1) {
        int t = lds[threadIdx.x];
        int a = (threadIdx.x >= off) ? lds[threadIdx.x - off] : 0;
        __syncthreads();
        lds[threadIdx.x] = t + a;
        __syncthreads();
    }
    if (threadIdx.x < nb) boff[threadIdx.x] = lds[threadIdx.x] - v;   // exclusive
    if (threadIdx.x == 0) rowptr[NN] = NE;
}

__global__ __launch_bounds__(256) void k_scan3(const int* __restrict__ deg,
                                               const int* __restrict__ boff,
                                               int* __restrict__ rowptr) {
    __shared__ int lds[256];
    int i = blockIdx.x * 256 + threadIdx.x;
    int v = (i < NN) ? deg[i] : 0;
    int incl = block_incl_scan(v, lds);
    if (i < NN) rowptr[i] = incl - v + boff[blockIdx.x];
}

// bucket fill: eidx[pos]=src, ecoef[pos]=dinv[src]
__global__ __launch_bounds__(256) void k_fill(
    const int* __restrict__ src, const int* __restrict__ dst,
    const float* __restrict__ dinv, const int* __restrict__ rowptr,
    int* __restrict__ cursor, int* __restrict__ eidx, float* __restrict__ ecoef)
{
    int e = blockIdx.x * 256 + threadIdx.x;
    if (e < NE) {
        const int d = dst[e], s = src[e];
        const int pos = rowptr[d] + atomicAdd(cursor + d, 1);
        eidx[pos] = s;
        ecoef[pos] = dinv[s];
    }
}

// ---------------------------------------------------------------------------
// bf16 MFMA GEMM: C[M][HID](bf16) = A[M][K](fp32, optional BN+ReLU) * Bt^T
template<int K, int MODE>
__global__ __launch_bounds__(256) void k_gemm(
    const float* __restrict__ A, const unsigned short* __restrict__ Bt,
    unsigned short* __restrict__ C,
    const float* __restrict__ scale, const float* __restrict__ bias, int M)
{
    constexpr int BM = 128, BN = 128, BK = 32, LD = 40;
    __shared__ __align__(16) unsigned short As[BM * LD];
    __shared__ __align__(16) unsigned short Bs[BN * LD];
    const int tid = threadIdx.x;
    const int lane = tid & 63;
    const int wid  = tid >> 6;
    const int wm = wid & 1, wn = wid >> 1;
    const int l15 = lane & 15, lq = lane >> 4;
    const int row0 = blockIdx.y * BM, col0 = blockIdx.x * BN;

    floatx4 acc[4][4] = {};

    const int ar = tid >> 3;
    const int ak = (tid & 7) * 4;
    const int bn_ = tid >> 2;
    const int bk  = (tid & 3) * 8;

    for (int k0 = 0; k0 < K; k0 += BK) {
        float4 sv, bv;
        if (MODE) {
            sv = *(const float4*)(scale + k0 + ak);
            bv = *(const float4*)(bias  + k0 + ak);
        }
        #pragma unroll
        for (int p = 0; p < 4; ++p) {
            const int row  = p * 32 + ar;
            const int grow = row0 + row;
            float x0 = 0.f, x1 = 0.f, x2 = 0.f, x3 = 0.f;
            if (grow < M) {
                float4 v = *(const float4*)(A + (size_t)grow * K + k0 + ak);
                if (MODE) {
                    x0 = fmaxf(v.x * sv.x + bv.x, 0.f);
                    x1 = fmaxf(v.y * sv.y + bv.y, 0.f);
                    x2 = fmaxf(v.z * sv.z + bv.z, 0.f);
                    x3 = fmaxf(v.w * sv.w + bv.w, 0.f);
                } else { x0 = v.x; x1 = v.y; x2 = v.z; x3 = v.w; }
            }
            ushort4 o;
            o.x = f2b(x0); o.y = f2b(x1); o.z = f2b(x2); o.w = f2b(x3);
            *(ushort4*)(As + row * LD + ak) = o;
        }
        #pragma unroll
        for (int p = 0; p < 2; ++p) {
            const int n = p * 64 + bn_;
            *(float4*)(Bs + n * LD + bk) =
                *(const float4*)(Bt + (size_t)(col0 + n) * K + k0 + bk);
        }
        __syncthreads();

        short8 af[4], bf[4];
        #pragma unroll
        for (int i = 0; i < 4; ++i)
            af[i] = *(const short8*)(As + (wm * 64 + i * 16 + l15) * LD + lq * 8);
        #pragma unroll
        for (int j = 0; j < 4; ++j)
            bf[j] = *(const short8*)(Bs + (wn * 64 + j * 16 + l15) * LD + lq * 8);
        #pragma unroll
        for (int i = 0; i < 4; ++i)
            #pragma unroll
            for (int j = 0; j < 4; ++j)
                acc[i][j] = __builtin_amdgcn_mfma_f32_16x16x32_bf16(af[i], bf[j], acc[i][j], 0, 0, 0);
        __syncthreads();
    }

    #pragma unroll
    for (int i = 0; i < 4; ++i) {
        #pragma unroll
        for (int r = 0; r < 4; ++r) {
            const int m = row0 + wm * 64 + i * 16 + lq * 4 + r;
            if (m < M) {
                #pragma unroll
                for (int j = 0; j < 4; ++j) {
                    const int c = col0 + wn * 64 + j * 16 + l15;
                    C[(size_t)m * HID + c] = f2b(acc[i][j][r]);
                }
            }
        }
    }
}

// ---------------------------------------------------------------------------
// CSR gather: AGG[n] = sum_{e in bucket(n)} coef*H[src] + H[n]*dinv[n]^2
// One wave per node (grid-stride). Fuses BN sum/sumsq accumulation.
__global__ __launch_bounds__(256) void k_gather(
    const unsigned short* __restrict__ H, const int* __restrict__ eidx,
    const float* __restrict__ ecoef, const int* __restrict__ rowptr,
    const float* __restrict__ dinv, float* __restrict__ AGG,
    float* __restrict__ bn_acc)
{
    __shared__ float ls[512];
    const int tid = threadIdx.x, lane = tid & 63, w = tid >> 6;
    const int c0 = lane * 4;
    float sx = 0.f, sy = 0.f, sz = 0.f, sw = 0.f;
    float qx = 0.f, qy = 0.f, qz = 0.f, qw = 0.f;

    for (int n = blockIdx.x * 4 + w; n < NN; n += gridDim.x * 4) {
        const int beg = rowptr[n], end = rowptr[n + 1];
        const float di = dinv[n];
        float ax = 0.f, ay = 0.f, az = 0.f, aw = 0.f;
        int j = beg;
        for (; j + 2 <= end; j += 2) {
            const int s0 = eidx[j], s1 = eidx[j + 1];
            const float cf0 = ecoef[j] * di, cf1 = ecoef[j + 1] * di;
            const ushort4 h0 = *(const ushort4*)(H + (size_t)s0 * HID + c0);
            const ushort4 h1 = *(const ushort4*)(H + (size_t)s1 * HID + c0);
            ax += b2f(h0.x) * cf0 + b2f(h1.x) * cf1;
            ay += b2f(h0.y) * cf0 + b2f(h1.y) * cf1;
            az += b2f(h0.z) * cf0 + b2f(h1.z) * cf1;
            aw += b2f(h0.w) * cf0 + b2f(h1.w) * cf1;
        }
        if (j < end) {
            const int s0 = eidx[j];
            const float cf0 = ecoef[j] * di;
            const ushort4 h0 = *(const ushort4*)(H + (size_t)s0 * HID + c0);
            ax += b2f(h0.x) * cf0; ay += b2f(h0.y) * cf0;
            az += b2f(h0.z) * cf0; aw += b2f(h0.w) * cf0;
        }
        // self loop: + H[n] * dinv^2
        const float cs = di * di;
        const ushort4 hs = *(const ushort4*)(H + (size_t)n * HID + c0);
        ax += b2f(hs.x) * cs; ay += b2f(hs.y) * cs;
        az += b2f(hs.z) * cs; aw += b2f(hs.w) * cs;

        float4 o; o.x = ax; o.y = ay; o.z = az; o.w = aw;
        *(float4*)(AGG + (size_t)n * HID + c0) = o;

        sx += ax; sy += ay; sz += az; sw += aw;
        qx += ax * ax; qy += ay * ay; qz += az * az; qw += aw * aw;
    }

    // block-level BN stat reduction: 4 waves share column mapping
    ls[tid] = 0.f; ls[tid + 256] = 0.f;
    __syncthreads();
    atomicAdd(&ls[c0 + 0], sx); atomicAdd(&ls[c0 + 1], sy);
    atomicAdd(&ls[c0 + 2], sz); atomicAdd(&ls[c0 + 3], sw);
    atomicAdd(&ls[256 + c0 + 0], qx); atomicAdd(&ls[256 + c0 + 1], qy);
    atomicAdd(&ls[256 + c0 + 2], qz); atomicAdd(&ls[256 + c0 + 3], qw);
    __syncthreads();
    atomicAdd(bn_acc + tid, ls[tid]);
    atomicAdd(bn_acc + 256 + tid, ls[tid + 256]);
}

__global__ void k_bnparam(const float* __restrict__ bn_acc,
                          const float* __restrict__ g, const float* __restrict__ be,
                          float* __restrict__ scale, float* __restrict__ bias)
{
    const int c = threadIdx.x;
    const float inv_n = 1.f / (float)NN;
    const float mu  = bn_acc[c] * inv_n;
    const float var = bn_acc[256 + c] * inv_n - mu * mu;
    const float sc  = g[c] * rsqrtf(var + BN_EPS);
    scale[c] = sc;
    bias[c]  = be[c] - sc * mu;
}

// final BN2 + ReLU -> d_out (fp32)
__global__ __launch_bounds__(256) void k_apply(
    const float* __restrict__ AGG, const float* __restrict__ scale,
    const float* __restrict__ bias, float* __restrict__ out)
{
    const int gid = blockIdx.x * 256 + threadIdx.x;
    if (gid < NN * (HID / 4)) {
        const int c4 = (gid & 63) * 4;
        float4 v  = *(const float4*)(AGG + (size_t)gid * 4);
        float4 sc = *(const float4*)(scale + c4);
        float4 bi = *(const float4*)(bias + c4);
        float4 o;
        o.x = fmaxf(v.x * sc.x + bi.x, 0.f);
        o.y = fmaxf(v.y * sc.y + bi.y, 0.f);
        o.z = fmaxf(v.z * sc.z + bi.z, 0.f);
        o.w = fmaxf(v.w * sc.w + bi.w, 0.f);
        *(float4*)(out + (size_t)gid * 4) = o;
    }
}

// ---------------------------------------------------------------------------
extern "C" void kernel_launch(void* const* d_in, const int* in_sizes, int n_in,
                              void* d_out, int out_size, void* d_ws, size_t ws_size,
                              hipStream_t stream)
{
    const float* x   = (const float*)d_in[0];
    const int*   ei  = (const int*)d_in[1];
    const float* W1  = (const float*)d_in[2];
    const float* g1  = (const float*)d_in[4];
    const float* be1 = (const float*)d_in[5];
    const float* W2  = (const float*)d_in[6];
    const float* g2  = (const float*)d_in[8];
    const float* be2 = (const float*)d_in[9];
    float* out = (float*)d_out;
    const int* srcp = ei;
    const int* dstp = ei + NE;

    constexpr int NB = (NN + 255) / 256;   // 391 scan blocks

    char* p = (char*)d_ws;
    float*          AGG    = (float*)p;           p += (size_t)NN * HID * 4;   // 102.4 MB
    unsigned short* H      = (unsigned short*)p;  p += (size_t)NN * HID * 2;   // 51.2 MB
    int*            deg    = (int*)p;             p += (size_t)NN * 4;
    float*          dinv   = (float*)p;           p += (size_t)NN * 4;
    int*            rowptr = (int*)p;             p += (size_t)(NN + 1) * 4;
    int*            cursor = (int*)p;             p += (size_t)NN * 4;
    int*            eidx   = (int*)p;             p += (size_t)NE * 4;         // 3.2 MB
    float*          ecoef  = (float*)p;           p += (size_t)NE * 4;         // 3.2 MB
    int*            bsum   = (int*)p;             p += 512 * 4;
    int*            boff   = (int*)p;             p += 512 * 4;
    unsigned short* W1t    = (unsigned short*)p;  p += (size_t)KIN * HID * 2;
    unsigned short* W2t    = (unsigned short*)p;  p += (size_t)HID * HID * 2;
    float*          bn1    = (float*)p;           p += 512 * 4;
    float*          bn2    = (float*)p;           p += 512 * 4;
    float*          sc1    = (float*)p;           p += 256 * 4;
    float*          bi1    = (float*)p;           p += 256 * 4;
    float*          sc2    = (float*)p;           p += 256 * 4;
    float*          bi2    = (float*)p;           p += 256 * 4;

    hipMemsetAsync(deg, 0, (size_t)NN * 4, stream);
    hipMemsetAsync(cursor, 0, (size_t)NN * 4, stream);
    hipMemsetAsync(bn1, 0, 1024 * 4, stream);   // bn1 + bn2 contiguous

    k_wt<<<KIN, HID, 0, stream>>>(W1, W1t, KIN);
    k_wt<<<HID, HID, 0, stream>>>(W2, W2t, HID);

    // graph prep: count -> dinv -> scan -> fill
    k_count<<<(NE + 255) / 256, 256, 0, stream>>>(dstp, deg);
    k_dinv<<<(NN + 255) / 256, 256, 0, stream>>>(deg, dinv);
    k_scan1<<<NB, 256, 0, stream>>>(deg, bsum);
    k_scan2<<<1, 512, 0, stream>>>(bsum, boff, NB, rowptr);
    k_scan3<<<NB, 256, 0, stream>>>(deg, boff, rowptr);
    k_fill<<<(NE + 255) / 256, 256, 0, stream>>>(srcp, dstp, dinv, rowptr, cursor, eidx, ecoef);

    dim3 ggrid(HID / 128, (NN + 127) / 128);   // (2, 782)

    // ---- layer 1 ----
    k_gemm<KIN, 0><<<ggrid, 256, 0, stream>>>(x, W1t, H, nullptr, nullptr, NN);
    k_gather<<<2048, 256, 0, stream>>>(H, eidx, ecoef, rowptr, dinv, AGG, bn1);
    k_bnparam<<<1, 256, 0, stream>>>(bn1, g1, be1, sc1, bi1);

    // ---- layer 2 (BN1+ReLU fused into GEMM2 A-stage) ----
    k_gemm<HID, 1><<<ggrid, 256, 0, stream>>>(AGG, W2t, H, sc1, bi1, NN);
    k_gather<<<2048, 256, 0, stream>>>(H, eidx, ecoef, rowptr, dinv, AGG, bn2);
    k_bnparam<<<1, 256, 0, stream>>>(bn2, g2, be2, sc2, bi2);
    k_apply<<<(NN * HID / 4 + 255) / 256, 256, 0, stream>>>(AGG, sc2, bi2, out);
}

// Round 3
// 678.068 us; speedup vs baseline: 8.7526x; 1.2218x over previous
//
#include <hip/hip_runtime.h>
#include <hip/hip_bf16.h>

#define NN  100000   // nodes
#define NE  800000   // edges
#define KIN 384      // input dim
#define HID 256      // hidden dim
#define BN_EPS 1e-5f

typedef __attribute__((ext_vector_type(4))) float floatx4;
typedef __attribute__((ext_vector_type(8))) short short8;

__device__ __forceinline__ unsigned short f2b(float f) {
    union { float f; unsigned int u; } v; v.f = f;
    unsigned int r = v.u + 0x7fffu + ((v.u >> 16) & 1u);   // round-to-nearest-even
    return (unsigned short)(r >> 16);
}
__device__ __forceinline__ float b2f(unsigned short h) {
    union { unsigned int u; float f; } v; v.u = ((unsigned int)h) << 16;
    return v.f;
}

// ---------------------------------------------------------------------------
// both weight transposes in one launch: W[K][HID] fp32 -> Wt[HID][K] bf16
__global__ void k_wt2(const float* __restrict__ W1, unsigned short* __restrict__ W1t,
                      const float* __restrict__ W2, unsigned short* __restrict__ W2t) {
    const int n = threadIdx.x;
    const int k = blockIdx.x;
    if (k < KIN) W1t[(size_t)n * KIN + k] = f2b(W1[(size_t)k * HID + n]);
    else {
        const int k2 = k - KIN;
        W2t[(size_t)n * HID + k2] = f2b(W2[(size_t)k2 * HID + n]);
    }
}

// in-degree count over dst
__global__ void k_count(const int* __restrict__ dst, int* __restrict__ deg) {
    int i = blockIdx.x * 256 + threadIdx.x;
    if (i < NE) atomicAdd(deg + dst[i], 1);
}

// ---------------------------------------------------------------------------
// hierarchical exclusive scan of deg[NN] -> rowptr[NN+1]; dinv fused in scan1
__device__ __forceinline__ int block_incl_scan(int v, int* lds) {  // 256 threads
    lds[threadIdx.x] = v; __syncthreads();
    #pragma unroll
    for (int off = 1; off < 256; off <<= 1) {
        int t = lds[threadIdx.x];
        int a = (threadIdx.x >= off) ? lds[threadIdx.x - off] : 0;
        __syncthreads();
        lds[threadIdx.x] = t + a;
        __syncthreads();
    }
    return lds[threadIdx.x];
}

__global__ __launch_bounds__(256) void k_scan1(const int* __restrict__ deg,
                                               int* __restrict__ bsum,
                                               float* __restrict__ dinv) {
    __shared__ int lds[256];
    int i = blockIdx.x * 256 + threadIdx.x;
    int v = (i < NN) ? deg[i] : 0;
    if (i < NN) dinv[i] = rsqrtf((float)(v + 1));   // deg + self loop
    int incl = block_incl_scan(v, lds);
    if (threadIdx.x == 255) bsum[blockIdx.x] = incl;
}

__global__ __launch_bounds__(512) void k_scan2(const int* __restrict__ bsum,
                                               int* __restrict__ boff, int nb,
                                               int* __restrict__ rowptr) {
    __shared__ int lds[512];
    int v = (threadIdx.x < nb) ? bsum[threadIdx.x] : 0;
    lds[threadIdx.x] = v; __syncthreads();
    #pragma unroll
    for (int off = 1; off < 512; off <<= 1) {
        int t = lds[threadIdx.x];
        int a = (threadIdx.x >= off) ? lds[threadIdx.x - off] : 0;
        __syncthreads();
        lds[threadIdx.x] = t + a;
        __syncthreads();
    }
    if (threadIdx.x < nb) boff[threadIdx.x] = lds[threadIdx.x] - v;   // exclusive
    if (threadIdx.x == 0) rowptr[NN] = NE;
}

__global__ __launch_bounds__(256) void k_scan3(const int* __restrict__ deg,
                                               const int* __restrict__ boff,
                                               int* __restrict__ rowptr) {
    __shared__ int lds[256];
    int i = blockIdx.x * 256 + threadIdx.x;
    int v = (i < NN) ? deg[i] : 0;
    int incl = block_incl_scan(v, lds);
    if (i < NN) rowptr[i] = incl - v + boff[blockIdx.x];
}

// bucket fill: packed record {src, dinv[src]} per edge, 8B store
__global__ __launch_bounds__(256) void k_fill(
    const int* __restrict__ src, const int* __restrict__ dst,
    const float* __restrict__ dinv, const int* __restrict__ rowptr,
    int* __restrict__ cursor, int2* __restrict__ epk)
{
    int e = blockIdx.x * 256 + threadIdx.x;
    if (e < NE) {
        const int d = dst[e], s = src[e];
        const int pos = rowptr[d] + atomicAdd(cursor + d, 1);
        int2 rec; rec.x = s; rec.y = __float_as_int(dinv[s]);
        epk[pos] = rec;
    }
}

// ---------------------------------------------------------------------------
// bf16 MFMA GEMM, full-width tile: C[M][256](bf16) = A[M][K] * Bt^T
// BM=128, BN=256(=HID), 512 threads / 8 waves of 64x64. A read ONCE per tile.
// ABF16: A is bf16 (else fp32). MODE: A' = relu(A*scale[k]+bias[k]) (BN fused).
template<int K, int MODE, int ABF16>
__global__ __launch_bounds__(512) void k_gemm(
    const void* __restrict__ Av, const unsigned short* __restrict__ Bt,
    unsigned short* __restrict__ C,
    const float* __restrict__ scale, const float* __restrict__ bias, int M)
{
    constexpr int BM = 128, BK = 32, LD = 40;   // LD pad kills bank conflicts
    __shared__ __align__(16) unsigned short As[BM * LD];
    __shared__ __align__(16) unsigned short Bs[HID * LD];
    const int tid = threadIdx.x;
    const int lane = tid & 63;
    const int wid  = tid >> 6;           // 0..7
    const int wm = wid & 1, wn = wid >> 1;   // 2 x 4 wave grid
    const int l15 = lane & 15, lq = lane >> 4;
    const int row0 = blockIdx.x * BM;

    floatx4 acc[4][4] = {};

    const int ar  = tid >> 3;        // 0..63  (fp32 A staging row)
    const int ak  = (tid & 7) * 4;   // 0..28
    const int ar2 = tid >> 2;        // 0..127 (bf16 A staging row)
    const int ak2 = (tid & 3) * 8;   // 0,8,16,24
    const int bn_ = tid >> 2;        // 0..127
    const int bk  = (tid & 3) * 8;

    for (int k0 = 0; k0 < K; k0 += BK) {
        // ---- stage A ----
        if (ABF16) {
            const unsigned short* A = (const unsigned short*)Av;
            const int grow = row0 + ar2;
            float x[8];
            if (grow < M) {
                short8 v = *(const short8*)(A + (size_t)grow * K + k0 + ak2);
                #pragma unroll
                for (int t = 0; t < 8; ++t) x[t] = b2f((unsigned short)v[t]);
                if (MODE) {
                    float4 s0 = *(const float4*)(scale + k0 + ak2);
                    float4 s1 = *(const float4*)(scale + k0 + ak2 + 4);
                    float4 b0 = *(const float4*)(bias  + k0 + ak2);
                    float4 b1 = *(const float4*)(bias  + k0 + ak2 + 4);
                    x[0] = fmaxf(x[0] * s0.x + b0.x, 0.f);
                    x[1] = fmaxf(x[1] * s0.y + b0.y, 0.f);
                    x[2] = fmaxf(x[2] * s0.z + b0.z, 0.f);
                    x[3] = fmaxf(x[3] * s0.w + b0.w, 0.f);
                    x[4] = fmaxf(x[4] * s1.x + b1.x, 0.f);
                    x[5] = fmaxf(x[5] * s1.y + b1.y, 0.f);
                    x[6] = fmaxf(x[6] * s1.z + b1.z, 0.f);
                    x[7] = fmaxf(x[7] * s1.w + b1.w, 0.f);
                }
            } else {
                #pragma unroll
                for (int t = 0; t < 8; ++t) x[t] = 0.f;
            }
            short8 o;
            #pragma unroll
            for (int t = 0; t < 8; ++t) o[t] = (short)f2b(x[t]);
            *(short8*)(As + ar2 * LD + ak2) = o;
        } else {
            const float* A = (const float*)Av;
            #pragma unroll
            for (int p = 0; p < 2; ++p) {
                const int row  = p * 64 + ar;
                const int grow = row0 + row;
                float x0 = 0.f, x1 = 0.f, x2 = 0.f, x3 = 0.f;
                if (grow < M) {
                    float4 v = *(const float4*)(A + (size_t)grow * K + k0 + ak);
                    x0 = v.x; x1 = v.y; x2 = v.z; x3 = v.w;
                }
                ushort4 o;
                o.x = f2b(x0); o.y = f2b(x1); o.z = f2b(x2); o.w = f2b(x3);
                *(ushort4*)(As + row * LD + ak) = o;
            }
        }
        // ---- stage B: 256x32 bf16 copy-through ----
        #pragma unroll
        for (int p = 0; p < 2; ++p) {
            const int n = p * 128 + bn_;
            *(float4*)(Bs + n * LD + bk) =
                *(const float4*)(Bt + (size_t)n * K + k0 + bk);
        }
        __syncthreads();

        short8 af[4], bf[4];
        #pragma unroll
        for (int i = 0; i < 4; ++i)
            af[i] = *(const short8*)(As + (wm * 64 + i * 16 + l15) * LD + lq * 8);
        #pragma unroll
        for (int j = 0; j < 4; ++j)
            bf[j] = *(const short8*)(Bs + (wn * 64 + j * 16 + l15) * LD + lq * 8);
        #pragma unroll
        for (int i = 0; i < 4; ++i)
            #pragma unroll
            for (int j = 0; j < 4; ++j)
                acc[i][j] = __builtin_amdgcn_mfma_f32_16x16x32_bf16(af[i], bf[j], acc[i][j], 0, 0, 0);
        __syncthreads();
    }

    // epilogue: C/D layout col=lane&15, row=(lane>>4)*4+reg
    #pragma unroll
    for (int i = 0; i < 4; ++i) {
        #pragma unroll
        for (int r = 0; r < 4; ++r) {
            const int m = row0 + wm * 64 + i * 16 + lq * 4 + r;
            if (m < M) {
                #pragma unroll
                for (int j = 0; j < 4; ++j) {
                    const int c = wn * 64 + j * 16 + l15;
                    C[(size_t)m * HID + c] = f2b(acc[i][j][r]);
                }
            }
        }
    }
}

// ---------------------------------------------------------------------------
// CSR gather: AGGb[n] = sum coef*H[src] + H[n]*dinv^2 (bf16 out, fp32 stats).
// One wave per node, 4-deep row-load pipeline, packed 8B edge records.
__global__ __launch_bounds__(256) void k_gather(
    const unsigned short* __restrict__ H, const int2* __restrict__ epk,
    const int* __restrict__ rowptr, const float* __restrict__ dinv,
    unsigned short* __restrict__ AGGb, float* __restrict__ bn_acc)
{
    __shared__ float ls[512];
    const int tid = threadIdx.x, lane = tid & 63, w = tid >> 6;
    const int c0 = lane * 4;
    float sx = 0.f, sy = 0.f, sz = 0.f, sw = 0.f;
    float qx = 0.f, qy = 0.f, qz = 0.f, qw = 0.f;

    for (int n = blockIdx.x * 4 + w; n < NN; n += gridDim.x * 4) {
        const int beg = rowptr[n], end = rowptr[n + 1];
        const float di = dinv[n];
        float ax = 0.f, ay = 0.f, az = 0.f, aw = 0.f;
        int j = beg;
        for (; j + 4 <= end; j += 4) {
            const int2 e0 = epk[j], e1 = epk[j + 1], e2 = epk[j + 2], e3 = epk[j + 3];
            const ushort4 h0 = *(const ushort4*)(H + (size_t)e0.x * HID + c0);
            const ushort4 h1 = *(const ushort4*)(H + (size_t)e1.x * HID + c0);
            const ushort4 h2 = *(const ushort4*)(H + (size_t)e2.x * HID + c0);
            const ushort4 h3 = *(const ushort4*)(H + (size_t)e3.x * HID + c0);
            const float f0 = __int_as_float(e0.y) * di, f1 = __int_as_float(e1.y) * di;
            const float f2 = __int_as_float(e2.y) * di, f3 = __int_as_float(e3.y) * di;
            ax += b2f(h0.x) * f0 + b2f(h1.x) * f1 + b2f(h2.x) * f2 + b2f(h3.x) * f3;
            ay += b2f(h0.y) * f0 + b2f(h1.y) * f1 + b2f(h2.y) * f2 + b2f(h3.y) * f3;
            az += b2f(h0.z) * f0 + b2f(h1.z) * f1 + b2f(h2.z) * f2 + b2f(h3.z) * f3;
            aw += b2f(h0.w) * f0 + b2f(h1.w) * f1 + b2f(h2.w) * f2 + b2f(h3.w) * f3;
        }
        for (; j < end; ++j) {
            const int2 e0 = epk[j];
            const float f0 = __int_as_float(e0.y) * di;
            const ushort4 h0 = *(const ushort4*)(H + (size_t)e0.x * HID + c0);
            ax += b2f(h0.x) * f0; ay += b2f(h0.y) * f0;
            az += b2f(h0.z) * f0; aw += b2f(h0.w) * f0;
        }
        // self loop: + H[n] * dinv^2
        const float cs = di * di;
        const ushort4 hs = *(const ushort4*)(H + (size_t)n * HID + c0);
        ax += b2f(hs.x) * cs; ay += b2f(hs.y) * cs;
        az += b2f(hs.z) * cs; aw += b2f(hs.w) * cs;

        ushort4 o;
        o.x = f2b(ax); o.y = f2b(ay); o.z = f2b(az); o.w = f2b(aw);
        *(ushort4*)(AGGb + (size_t)n * HID + c0) = o;

        sx += ax; sy += ay; sz += az; sw += aw;
        qx += ax * ax; qy += ay * ay; qz += az * az; qw += aw * aw;
    }

    // block-level BN stat reduction (4 waves share column mapping)
    ls[tid] = 0.f; ls[tid + 256] = 0.f;
    __syncthreads();
    atomicAdd(&ls[c0 + 0], sx); atomicAdd(&ls[c0 + 1], sy);
    atomicAdd(&ls[c0 + 2], sz); atomicAdd(&ls[c0 + 3], sw);
    atomicAdd(&ls[256 + c0 + 0], qx); atomicAdd(&ls[256 + c0 + 1], qy);
    atomicAdd(&ls[256 + c0 + 2], qz); atomicAdd(&ls[256 + c0 + 3], qw);
    __syncthreads();
    atomicAdd(bn_acc + tid, ls[tid]);
    atomicAdd(bn_acc + 256 + tid, ls[tid + 256]);
}

__global__ void k_bnparam(const float* __restrict__ bn_acc,
                          const float* __restrict__ g, const float* __restrict__ be,
                          float* __restrict__ scale, float* __restrict__ bias)
{
    const int c = threadIdx.x;
    const float inv_n = 1.f / (float)NN;
    const float mu  = bn_acc[c] * inv_n;
    const float var = bn_acc[256 + c] * inv_n - mu * mu;
    const float sc  = g[c] * rsqrtf(var + BN_EPS);
    scale[c] = sc;
    bias[c]  = be[c] - sc * mu;
}

// final BN2 + ReLU: bf16 AGG -> fp32 out
__global__ __launch_bounds__(256) void k_apply(
    const unsigned short* __restrict__ AGGb, const float* __restrict__ scale,
    const float* __restrict__ bias, float* __restrict__ out)
{
    const int gid = blockIdx.x * 256 + threadIdx.x;   // one ushort4 / thread
    if (gid < NN * (HID / 4)) {
        const int c4 = (gid & 63) * 4;
        ushort4 v = *(const ushort4*)(AGGb + (size_t)gid * 4);
        float4 sc = *(const float4*)(scale + c4);
        float4 bi = *(const float4*)(bias + c4);
        float4 o;
        o.x = fmaxf(b2f(v.x) * sc.x + bi.x, 0.f);
        o.y = fmaxf(b2f(v.y) * sc.y + bi.y, 0.f);
        o.z = fmaxf(b2f(v.z) * sc.z + bi.z, 0.f);
        o.w = fmaxf(b2f(v.w) * sc.w + bi.w, 0.f);
        *(float4*)(out + (size_t)gid * 4) = o;
    }
}

// ---------------------------------------------------------------------------
extern "C" void kernel_launch(void* const* d_in, const int* in_sizes, int n_in,
                              void* d_out, int out_size, void* d_ws, size_t ws_size,
                              hipStream_t stream)
{
    const float* x   = (const float*)d_in[0];
    const int*   ei  = (const int*)d_in[1];
    const float* W1  = (const float*)d_in[2];
    const float* g1  = (const float*)d_in[4];
    const float* be1 = (const float*)d_in[5];
    const float* W2  = (const float*)d_in[6];
    const float* g2  = (const float*)d_in[8];
    const float* be2 = (const float*)d_in[9];
    float* out = (float*)d_out;
    const int* srcp = ei;
    const int* dstp = ei + NE;

    constexpr int NB = (NN + 255) / 256;   // 391 scan blocks

    char* p = (char*)d_ws;
    // zero-init region (single memset): deg, cursor, bn1, bn2
    int*            deg    = (int*)p;             p += (size_t)NN * 4;
    int*            cursor = (int*)p;             p += (size_t)NN * 4;
    float*          bn1    = (float*)p;           p += 512 * 4;
    float*          bn2    = (float*)p;           p += 512 * 4;
    const size_t zbytes = (size_t)NN * 8 + 4096;
    // rest
    unsigned short* AGGb   = (unsigned short*)p;  p += (size_t)NN * HID * 2;   // 51.2 MB
    unsigned short* H      = (unsigned short*)p;  p += (size_t)NN * HID * 2;   // 51.2 MB
    float*          dinv   = (float*)p;           p += (size_t)NN * 4;
    int*            rowptr = (int*)p;             p += (size_t)(NN + 1) * 4;
    int2*           epk    = (int2*)p;            p += (size_t)NE * 8;         // 6.4 MB
    int*            bsum   = (int*)p;             p += 512 * 4;
    int*            boff   = (int*)p;             p += 512 * 4;
    unsigned short* W1t    = (unsigned short*)p;  p += (size_t)KIN * HID * 2;
    unsigned short* W2t    = (unsigned short*)p;  p += (size_t)HID * HID * 2;
    float*          sc1    = (float*)p;           p += 256 * 4;
    float*          bi1    = (float*)p;           p += 256 * 4;
    float*          sc2    = (float*)p;           p += 256 * 4;
    float*          bi2    = (float*)p;           p += 256 * 4;

    hipMemsetAsync(deg, 0, zbytes, stream);

    k_wt2<<<KIN + HID, HID, 0, stream>>>(W1, W1t, W2, W2t);

    // graph prep: count -> scan(+dinv) -> fill
    k_count<<<(NE + 255) / 256, 256, 0, stream>>>(dstp, deg);
    k_scan1<<<NB, 256, 0, stream>>>(deg, bsum, dinv);
    k_scan2<<<1, 512, 0, stream>>>(bsum, boff, NB, rowptr);
    k_scan3<<<NB, 256, 0, stream>>>(deg, boff, rowptr);
    k_fill<<<(NE + 255) / 256, 256, 0, stream>>>(srcp, dstp, dinv, rowptr, cursor, epk);

    const int ggrid = (NN + 127) / 128;   // 782 row-tiles, full 256-col width

    // ---- layer 1 ----
    k_gemm<KIN, 0, 0><<<ggrid, 512, 0, stream>>>(x, W1t, H, nullptr, nullptr, NN);
    k_gather<<<2048, 256, 0, stream>>>(H, epk, rowptr, dinv, AGGb, bn1);
    k_bnparam<<<1, 256, 0, stream>>>(bn1, g1, be1, sc1, bi1);

    // ---- layer 2 (BN1+ReLU fused into GEMM2 A-stage, bf16 A) ----
    k_gemm<HID, 1, 1><<<ggrid, 512, 0, stream>>>(AGGb, W2t, H, sc1, bi1, NN);
    k_gather<<<2048, 256, 0, stream>>>(H, epk, rowptr, dinv, AGGb, bn2);
    k_bnparam<<<1, 256, 0, stream>>>(bn2, g2, be2, sc2, bi2);
    k_apply<<<(NN * (HID / 4) + 255) / 256, 256, 0, stream>>>(AGGb, sc2, bi2, out);
}

// Round 4
// 661.127 us; speedup vs baseline: 8.9768x; 1.0256x over previous
//
#include <hip/hip_runtime.h>
#include <hip/hip_bf16.h>

#define NN  100000   // nodes
#define NE  800000   // edges
#define KIN 384      // input dim
#define HID 256      // hidden dim
#define BN_EPS 1e-5f

typedef __attribute__((ext_vector_type(4))) float floatx4;
typedef __attribute__((ext_vector_type(8))) short short8;

__device__ __forceinline__ unsigned short f2b(float f) {
    union { float f; unsigned int u; } v; v.f = f;
    unsigned int r = v.u + 0x7fffu + ((v.u >> 16) & 1u);   // round-to-nearest-even
    return (unsigned short)(r >> 16);
}
__device__ __forceinline__ float b2f(unsigned short h) {
    union { unsigned int u; float f; } v; v.u = ((unsigned int)h) << 16;
    return v.f;
}

// ---------------------------------------------------------------------------
// both weight transposes in one launch: W[K][HID] fp32 -> Wt[HID][K] bf16
__global__ void k_wt2(const float* __restrict__ W1, unsigned short* __restrict__ W1t,
                      const float* __restrict__ W2, unsigned short* __restrict__ W2t) {
    const int n = threadIdx.x;
    const int k = blockIdx.x;
    if (k < KIN) W1t[(size_t)n * KIN + k] = f2b(W1[(size_t)k * HID + n]);
    else {
        const int k2 = k - KIN;
        W2t[(size_t)n * HID + k2] = f2b(W2[(size_t)k2 * HID + n]);
    }
}

// in-degree count over dst
__global__ void k_count(const int* __restrict__ dst, int* __restrict__ deg) {
    int i = blockIdx.x * 256 + threadIdx.x;
    if (i < NE) atomicAdd(deg + dst[i], 1);
}

// ---------------------------------------------------------------------------
// hierarchical exclusive scan of deg[NN] -> rowptr[NN+1]; dinv fused in scan1
__device__ __forceinline__ int block_incl_scan(int v, int* lds) {  // 256 threads
    lds[threadIdx.x] = v; __syncthreads();
    #pragma unroll
    for (int off = 1; off < 256; off <<= 1) {
        int t = lds[threadIdx.x];
        int a = (threadIdx.x >= off) ? lds[threadIdx.x - off] : 0;
        __syncthreads();
        lds[threadIdx.x] = t + a;
        __syncthreads();
    }
    return lds[threadIdx.x];
}

__global__ __launch_bounds__(256) void k_scan1(const int* __restrict__ deg,
                                               int* __restrict__ bsum,
                                               float* __restrict__ dinv) {
    __shared__ int lds[256];
    int i = blockIdx.x * 256 + threadIdx.x;
    int v = (i < NN) ? deg[i] : 0;
    if (i < NN) dinv[i] = rsqrtf((float)(v + 1));   // deg + self loop
    int incl = block_incl_scan(v, lds);
    if (threadIdx.x == 255) bsum[blockIdx.x] = incl;
}

__global__ __launch_bounds__(512) void k_scan2(const int* __restrict__ bsum,
                                               int* __restrict__ boff, int nb,
                                               int* __restrict__ rowptr) {
    __shared__ int lds[512];
    int v = (threadIdx.x < nb) ? bsum[threadIdx.x] : 0;
    lds[threadIdx.x] = v; __syncthreads();
    #pragma unroll
    for (int off = 1; off < 512; off <<= 1) {
        int t = lds[threadIdx.x];
        int a = (threadIdx.x >= off) ? lds[threadIdx.x - off] : 0;
        __syncthreads();
        lds[threadIdx.x] = t + a;
        __syncthreads();
    }
    if (threadIdx.x < nb) boff[threadIdx.x] = lds[threadIdx.x] - v;   // exclusive
    if (threadIdx.x == 0) rowptr[NN] = NE;
}

__global__ __launch_bounds__(256) void k_scan3(const int* __restrict__ deg,
                                               const int* __restrict__ boff,
                                               int* __restrict__ rowptr) {
    __shared__ int lds[256];
    int i = blockIdx.x * 256 + threadIdx.x;
    int v = (i < NN) ? deg[i] : 0;
    int incl = block_incl_scan(v, lds);
    if (i < NN) rowptr[i] = incl - v + boff[blockIdx.x];
}

// bucket fill: packed record {src, dinv[src]} per edge, 8B store
__global__ __launch_bounds__(256) void k_fill(
    const int* __restrict__ src, const int* __restrict__ dst,
    const float* __restrict__ dinv, const int* __restrict__ rowptr,
    int* __restrict__ cursor, int2* __restrict__ epk)
{
    int e = blockIdx.x * 256 + threadIdx.x;
    if (e < NE) {
        const int d = dst[e], s = src[e];
        const int pos = rowptr[d] + atomicAdd(cursor + d, 1);
        int2 rec; rec.x = s; rec.y = __float_as_int(dinv[s]);
        epk[pos] = rec;
    }
}

// ---------------------------------------------------------------------------
// bf16 MFMA GEMM, full-width tile: C[M][256](bf16) = A[M][K] * Bt^T
// BM=128, BN=256(=HID), 512 threads / 8 waves of 64x64. A read ONCE per tile.
// ABF16: A is bf16. MODE: A' = relu(A*sc[k]+bi[k]), affine computed from raw
// bn_acc (sum/sumsq) into LDS once per block — no separate bnparam dispatch.
template<int K, int MODE, int ABF16>
__global__ __launch_bounds__(512) void k_gemm(
    const void* __restrict__ Av, const unsigned short* __restrict__ Bt,
    unsigned short* __restrict__ C,
    const float* __restrict__ bnacc, const float* __restrict__ g,
    const float* __restrict__ be, int M)
{
    constexpr int BM = 128, BK = 32, LD = 40;   // LD pad kills bank conflicts
    __shared__ __align__(16) unsigned short As[BM * LD];
    __shared__ __align__(16) unsigned short Bs[HID * LD];
    __shared__ float s_sc[HID], s_bi[HID];
    const int tid = threadIdx.x;
    const int lane = tid & 63;
    const int wid  = tid >> 6;           // 0..7
    const int wm = wid & 1, wn = wid >> 1;   // 2 x 4 wave grid
    const int l15 = lane & 15, lq = lane >> 4;
    const int row0 = blockIdx.x * BM;

    if (MODE) {
        if (tid < HID) {
            const float inv_n = 1.f / (float)NN;
            const float mu  = bnacc[tid] * inv_n;
            const float var = bnacc[HID + tid] * inv_n - mu * mu;
            const float s   = g[tid] * rsqrtf(var + BN_EPS);
            s_sc[tid] = s;
            s_bi[tid] = be[tid] - s * mu;
        }
        __syncthreads();
    }

    floatx4 acc[4][4] = {};

    const int ar  = tid >> 3;        // 0..63  (fp32 A staging row)
    const int ak  = (tid & 7) * 4;   // 0..28
    const int ar2 = tid >> 2;        // 0..127 (bf16 A staging row)
    const int ak2 = (tid & 3) * 8;   // 0,8,16,24
    const int bn_ = tid >> 2;        // 0..127
    const int bk  = (tid & 3) * 8;

    for (int k0 = 0; k0 < K; k0 += BK) {
        // ---- stage A ----
        if (ABF16) {
            const unsigned short* A = (const unsigned short*)Av;
            const int grow = row0 + ar2;
            float x[8];
            if (grow < M) {
                short8 v = *(const short8*)(A + (size_t)grow * K + k0 + ak2);
                #pragma unroll
                for (int t = 0; t < 8; ++t) x[t] = b2f((unsigned short)v[t]);
                if (MODE) {
                    float4 s0 = *(const float4*)(s_sc + k0 + ak2);
                    float4 s1 = *(const float4*)(s_sc + k0 + ak2 + 4);
                    float4 b0 = *(const float4*)(s_bi + k0 + ak2);
                    float4 b1 = *(const float4*)(s_bi + k0 + ak2 + 4);
                    x[0] = fmaxf(x[0] * s0.x + b0.x, 0.f);
                    x[1] = fmaxf(x[1] * s0.y + b0.y, 0.f);
                    x[2] = fmaxf(x[2] * s0.z + b0.z, 0.f);
                    x[3] = fmaxf(x[3] * s0.w + b0.w, 0.f);
                    x[4] = fmaxf(x[4] * s1.x + b1.x, 0.f);
                    x[5] = fmaxf(x[5] * s1.y + b1.y, 0.f);
                    x[6] = fmaxf(x[6] * s1.z + b1.z, 0.f);
                    x[7] = fmaxf(x[7] * s1.w + b1.w, 0.f);
                }
            } else {
                #pragma unroll
                for (int t = 0; t < 8; ++t) x[t] = 0.f;
            }
            short8 o;
            #pragma unroll
            for (int t = 0; t < 8; ++t) o[t] = (short)f2b(x[t]);
            *(short8*)(As + ar2 * LD + ak2) = o;
        } else {
            const float* A = (const float*)Av;
            #pragma unroll
            for (int p = 0; p < 2; ++p) {
                const int row  = p * 64 + ar;
                const int grow = row0 + row;
                float x0 = 0.f, x1 = 0.f, x2 = 0.f, x3 = 0.f;
                if (grow < M) {
                    float4 v = *(const float4*)(A + (size_t)grow * K + k0 + ak);
                    x0 = v.x; x1 = v.y; x2 = v.z; x3 = v.w;
                }
                ushort4 o;
                o.x = f2b(x0); o.y = f2b(x1); o.z = f2b(x2); o.w = f2b(x3);
                *(ushort4*)(As + row * LD + ak) = o;
            }
        }
        // ---- stage B: 256x32 bf16 copy-through ----
        #pragma unroll
        for (int p = 0; p < 2; ++p) {
            const int n = p * 128 + bn_;
            *(float4*)(Bs + n * LD + bk) =
                *(const float4*)(Bt + (size_t)n * K + k0 + bk);
        }
        __syncthreads();

        short8 af[4], bf[4];
        #pragma unroll
        for (int i = 0; i < 4; ++i)
            af[i] = *(const short8*)(As + (wm * 64 + i * 16 + l15) * LD + lq * 8);
        #pragma unroll
        for (int j = 0; j < 4; ++j)
            bf[j] = *(const short8*)(Bs + (wn * 64 + j * 16 + l15) * LD + lq * 8);
        #pragma unroll
        for (int i = 0; i < 4; ++i)
            #pragma unroll
            for (int j = 0; j < 4; ++j)
                acc[i][j] = __builtin_amdgcn_mfma_f32_16x16x32_bf16(af[i], bf[j], acc[i][j], 0, 0, 0);
        __syncthreads();
    }

    // epilogue: C/D layout col=lane&15, row=(lane>>4)*4+reg
    #pragma unroll
    for (int i = 0; i < 4; ++i) {
        #pragma unroll
        for (int r = 0; r < 4; ++r) {
            const int m = row0 + wm * 64 + i * 16 + lq * 4 + r;
            if (m < M) {
                #pragma unroll
                for (int j = 0; j < 4; ++j) {
                    const int c = wn * 64 + j * 16 + l15;
                    C[(size_t)m * HID + c] = f2b(acc[i][j][r]);
                }
            }
        }
    }
}

// ---------------------------------------------------------------------------
// CSR gather v3: one wave per node; lanes 0-31 even edges, 32-63 odd edges;
// each lane reads ushort8 (16B) of the H row => one dwordx4 covers 2 rows,
// 4x unroll = 8 rows in flight per wave. Self-loop loaded by upper half in
// parallel; one shfl_xor(32) folds halves. Fused BN sum/sumsq stats.
__global__ __launch_bounds__(256, 6) void k_gather(
    const unsigned short* __restrict__ H, const int2* __restrict__ epk,
    const int* __restrict__ rowptr, const float* __restrict__ dinv,
    unsigned short* __restrict__ AGGb, float* __restrict__ bn_acc)
{
    __shared__ float ls[512];
    const int tid = threadIdx.x, lane = tid & 63, w = tid >> 6;
    const int half = lane >> 5;          // 0 / 1
    const int l32  = lane & 31;
    const int c0   = l32 * 8;            // 8 columns per lane
    float s[8] = {}, q[8] = {};          // BN stats (lanes<32 valid at end)

    for (int n = blockIdx.x * 4 + w; n < NN; n += gridDim.x * 4) {
        const int beg = rowptr[n], end = rowptr[n + 1];
        const float di = dinv[n];
        float a[8] = {};
        int j = beg;
        for (; j + 8 <= end; j += 8) {       // 8 edges / iter, 8 rows in flight
            #pragma unroll
            for (int t = 0; t < 4; ++t) {
                const int2 e = epk[j + half + 2 * t];
                const float cf = __int_as_float(e.y) * di;
                const short8 h = *(const short8*)(H + (size_t)e.x * HID + c0);
                #pragma unroll
                for (int u = 0; u < 8; ++u)
                    a[u] += b2f((unsigned short)h[u]) * cf;
            }
        }
        for (; j + 2 <= end; j += 2) {       // pair tail
            const int2 e = epk[j + half];
            const float cf = __int_as_float(e.y) * di;
            const short8 h = *(const short8*)(H + (size_t)e.x * HID + c0);
            #pragma unroll
            for (int u = 0; u < 8; ++u)
                a[u] += b2f((unsigned short)h[u]) * cf;
        }
        if (j < end && half == 0) {          // odd last edge
            const int2 e = epk[j];
            const float cf = __int_as_float(e.y) * di;
            const short8 h = *(const short8*)(H + (size_t)e.x * HID + c0);
            #pragma unroll
            for (int u = 0; u < 8; ++u)
                a[u] += b2f((unsigned short)h[u]) * cf;
        }
        if (half == 1) {                     // self loop on upper half
            const float cs = di * di;
            const short8 h = *(const short8*)(H + (size_t)n * HID + c0);
            #pragma unroll
            for (int u = 0; u < 8; ++u)
                a[u] += b2f((unsigned short)h[u]) * cs;
        }
        #pragma unroll
        for (int u = 0; u < 8; ++u)
            a[u] += __shfl_xor(a[u], 32);    // fold halves (both get total)
        if (half == 0) {
            short8 o;
            #pragma unroll
            for (int u = 0; u < 8; ++u) o[u] = (short)f2b(a[u]);
            *(short8*)(AGGb + (size_t)n * HID + c0) = o;
            #pragma unroll
            for (int u = 0; u < 8; ++u) { s[u] += a[u]; q[u] += a[u] * a[u]; }
        }
    }

    // block-level BN stat reduction: 4 waves x lanes<32, 8 cols each
    ls[tid] = 0.f; ls[tid + 256] = 0.f;
    __syncthreads();
    if (half == 0) {
        #pragma unroll
        for (int u = 0; u < 8; ++u) {
            atomicAdd(&ls[c0 + u], s[u]);
            atomicAdd(&ls[256 + c0 + u], q[u]);
        }
    }
    __syncthreads();
    atomicAdd(bn_acc + tid, ls[tid]);
    atomicAdd(bn_acc + 256 + tid, ls[tid + 256]);
}

// final BN2 + ReLU: bf16 AGG -> fp32 out; affine computed inline from bn_acc
__global__ __launch_bounds__(256) void k_apply(
    const unsigned short* __restrict__ AGGb, const float* __restrict__ bnacc,
    const float* __restrict__ g, const float* __restrict__ be,
    float* __restrict__ out)
{
    const int gid = blockIdx.x * 256 + threadIdx.x;   // one ushort4 / thread
    if (gid < NN * (HID / 4)) {
        const int c4 = (gid & 63) * 4;
        float sc[4], bi[4];
        const float inv_n = 1.f / (float)NN;
        #pragma unroll
        for (int u = 0; u < 4; ++u) {
            const int c = c4 + u;
            const float mu  = bnacc[c] * inv_n;
            const float var = bnacc[HID + c] * inv_n - mu * mu;
            const float sv  = g[c] * rsqrtf(var + BN_EPS);
            sc[u] = sv; bi[u] = be[c] - sv * mu;
        }
        ushort4 v = *(const ushort4*)(AGGb + (size_t)gid * 4);
        float4 o;
        o.x = fmaxf(b2f(v.x) * sc[0] + bi[0], 0.f);
        o.y = fmaxf(b2f(v.y) * sc[1] + bi[1], 0.f);
        o.z = fmaxf(b2f(v.z) * sc[2] + bi[2], 0.f);
        o.w = fmaxf(b2f(v.w) * sc[3] + bi[3], 0.f);
        *(float4*)(out + (size_t)gid * 4) = o;
    }
}

// ---------------------------------------------------------------------------
extern "C" void kernel_launch(void* const* d_in, const int* in_sizes, int n_in,
                              void* d_out, int out_size, void* d_ws, size_t ws_size,
                              hipStream_t stream)
{
    const float* x   = (const float*)d_in[0];
    const int*   ei  = (const int*)d_in[1];
    const float* W1  = (const float*)d_in[2];
    const float* g1  = (const float*)d_in[4];
    const float* be1 = (const float*)d_in[5];
    const float* W2  = (const float*)d_in[6];
    const float* g2  = (const float*)d_in[8];
    const float* be2 = (const float*)d_in[9];
    float* out = (float*)d_out;
    const int* srcp = ei;
    const int* dstp = ei + NE;

    constexpr int NB = (NN + 255) / 256;   // 391 scan blocks

    char* p = (char*)d_ws;
    // zero-init region (single memset): deg, cursor, bn1, bn2
    int*            deg    = (int*)p;             p += (size_t)NN * 4;
    int*            cursor = (int*)p;             p += (size_t)NN * 4;
    float*          bn1    = (float*)p;           p += 512 * 4;
    float*          bn2    = (float*)p;           p += 512 * 4;
    const size_t zbytes = (size_t)NN * 8 + 4096;
    // rest
    unsigned short* AGGb   = (unsigned short*)p;  p += (size_t)NN * HID * 2;   // 51.2 MB
    unsigned short* H      = (unsigned short*)p;  p += (size_t)NN * HID * 2;   // 51.2 MB
    float*          dinv   = (float*)p;           p += (size_t)NN * 4;
    int*            rowptr = (int*)p;             p += (size_t)(NN + 1) * 4;
    int2*           epk    = (int2*)p;            p += (size_t)NE * 8;         // 6.4 MB
    int*            bsum   = (int*)p;             p += 512 * 4;
    int*            boff   = (int*)p;             p += 512 * 4;
    unsigned short* W1t    = (unsigned short*)p;  p += (size_t)KIN * HID * 2;
    unsigned short* W2t    = (unsigned short*)p;  p += (size_t)HID * HID * 2;

    hipMemsetAsync(deg, 0, zbytes, stream);

    k_wt2<<<KIN + HID, HID, 0, stream>>>(W1, W1t, W2, W2t);

    // graph prep: count -> scan(+dinv) -> fill
    k_count<<<(NE + 255) / 256, 256, 0, stream>>>(dstp, deg);
    k_scan1<<<NB, 256, 0, stream>>>(deg, bsum, dinv);
    k_scan2<<<1, 512, 0, stream>>>(bsum, boff, NB, rowptr);
    k_scan3<<<NB, 256, 0, stream>>>(deg, boff, rowptr);
    k_fill<<<(NE + 255) / 256, 256, 0, stream>>>(srcp, dstp, dinv, rowptr, cursor, epk);

    const int ggrid = (NN + 127) / 128;   // 782 row-tiles, full 256-col width

    // ---- layer 1 ----
    k_gemm<KIN, 0, 0><<<ggrid, 512, 0, stream>>>(x, W1t, H, nullptr, nullptr, nullptr, NN);
    k_gather<<<1536, 256, 0, stream>>>(H, epk, rowptr, dinv, AGGb, bn1);

    // ---- layer 2 (BN1+ReLU fused into GEMM2 A-stage from raw bn stats) ----
    k_gemm<HID, 1, 1><<<ggrid, 512, 0, stream>>>(AGGb, W2t, H, bn1, g1, be1, NN);
    k_gather<<<1536, 256, 0, stream>>>(H, epk, rowptr, dinv, AGGb, bn2);
    k_apply<<<(NN * (HID / 4) + 255) / 256, 256, 0, stream>>>(AGGb, bn2, g2, be2, out);
}